// Round 11
// baseline (300.269 us; speedup 1.0000x reference)
//
#include <hip/hip_runtime.h>
#include <hip/hip_bf16.h>
#include <stdint.h>

#define BATCH  16384
#define GAMMA  0.01f

using f32x4  = __attribute__((ext_vector_type(4))) float;
using f32x16 = __attribute__((ext_vector_type(16))) float;
using bf16x8 = __attribute__((ext_vector_type(8))) __bf16;

#define MFMA32(a, b, c) __builtin_amdgcn_mfma_f32_32x32x16_bf16((a), (b), (c), 0, 0, 0)
#define BAR() asm volatile("s_barrier" ::: "memory")

// ---------- helpers ----------
__device__ __forceinline__ unsigned short f2bf(float f) {
  unsigned int u = __float_as_uint(f);
  unsigned int r = (u + 0x7fffu + ((u >> 16) & 1u)) >> 16;  // RNE
  return (unsigned short)r;
}
__device__ __forceinline__ float bf2f(unsigned short u) {
  return __uint_as_float(((unsigned int)u) << 16);
}
__device__ __forceinline__ float sigmoidf_(float x) {
  return 1.0f / (1.0f + __expf(-x));
}
__device__ __forceinline__ float tanhf_(float x) {
  float e = __expf(2.0f * x);
  return (e - 1.0f) / (e + 1.0f);
}
__device__ __forceinline__ void gload_lds16(const void* gsrc, void* ldst) {
  __builtin_amdgcn_global_load_lds(
      (const __attribute__((address_space(1))) void*)gsrc,
      (__attribute__((address_space(3))) void*)ldst, 16, 0, 0);
}

// =====================================================================
// R5-verified K-loop schedule. DO NOT MODIFY the STAGE/BAR/vmcnt/setprio
// skeleton: P1: STAGE_A(cn,1,k1) P2: STAGE_B(cn,0,k1) P3: STAGE_B(cn,1,k1)
// P4: STAGE_A(c,0,k2) + counted vmcnt(2); 2 barriers per phase.
// (R3=565, R6=942, R7=838, R8=715 TF -- all schedule deviations worse.)
//
// MFMA 32x32x16; wave tile 128x64 = 4 row-blocks x 2 col-blocks.
// LDS layout from stage (thread t = wave*64+lane writes linear t*8 shorts):
//   LDS[r][g] = src[r][g ^ (r&7)]   (r = row 0..255, g = granule 0..7)
// A-frag k-step s (K=16): lane holds row r31(+block), k = s*16+khalf*8+[0..7]
//   -> global granule G = 2s+khalf -> LDS short off = row*64 + (G^(r&7))*8.
// R10 BUG (absmax 1.95): reads added +16/+32/+48 on top of the granule
// term, double-counting k and running off the row. Fixed here: the
// swizzled granule term is the ONLY k-offset.
// C/D (m74/m101): col=lane&31, row=(reg&3)+8*(reg>>2)+4*(lane>>5).
// =====================================================================
#define GEMM_PREAMBLE(X_, W_, lda_, K_, N_)                                    \
  __shared__ unsigned short As[2 * 16384];                                     \
  __shared__ unsigned short Bs[2 * 16384];                                     \
  const int qq  = gridDim.x >> 3;                                              \
  const int swz = (blockIdx.x & 7) * qq + (blockIdx.x >> 3);                   \
  const int tiles_n = (N_) >> 8;                                               \
  const int brow = swz / tiles_n;                                              \
  const int bcol = swz % tiles_n;                                              \
  const int t    = threadIdx.x;                                                \
  const int lane = t & 63;                                                     \
  const int wave = t >> 6;                                                     \
  const int wm   = wave >> 2;                                                  \
  const int wn   = wave & 3;                                                   \
  const int srow = t >> 3;                                                     \
  const int sg   = (t & 7) ^ (srow & 7);                                       \
  const unsigned short* aSrc = (X_) + (size_t)(brow * 256 + srow) * (lda_) + sg * 8; \
  const unsigned short* bSrc = (W_) + (size_t)(bcol * 256 + srow) * (K_) + sg * 8;   \
  const int wofs = wave * 512;                                                 \
  auto STAGE_A = [&](int buf, int h, int k0) {                                 \
    gload_lds16(aSrc + (size_t)(h * 128) * (lda_) + k0,                        \
                As + buf * 16384 + (h * 128) * 64 + wofs);                     \
    gload_lds16(aSrc + (size_t)(h * 128 + 64) * (lda_) + k0,                   \
                As + buf * 16384 + (h * 128 + 64) * 64 + wofs);                \
  };                                                                           \
  auto STAGE_B = [&](int buf, int h, int k0) {                                 \
    gload_lds16(bSrc + (size_t)(h * 128) * (K_) + k0,                          \
                Bs + buf * 16384 + (h * 128) * 64 + wofs);                     \
    gload_lds16(bSrc + (size_t)(h * 128 + 64) * (K_) + k0,                     \
                Bs + buf * 16384 + (h * 128 + 64) * 64 + wofs);                \
  };

#define GEMM_KLOOP_BODY(K_)                                                    \
  const int r31   = lane & 31;                                                 \
  const int khalf = lane >> 5;                                                 \
  const int rsw8  = r31 & 7;                                                   \
  const int gA0 = ((0 + khalf) ^ rsw8) * 8;  /* s=0: granule 0|1 */            \
  const int gA1 = ((2 + khalf) ^ rsw8) * 8;  /* s=1: granule 2|3 */            \
  const int gA2 = ((4 + khalf) ^ rsw8) * 8;  /* s=2: granule 4|5 */            \
  const int gA3 = ((6 + khalf) ^ rsw8) * 8;  /* s=3: granule 6|7 */            \
  const int a32 = (wm * 128 + r31) * 64;                                       \
  const int b32 = (wn * 64 + r31) * 64;                                        \
  f32x16 acc[4][2] = {};                                                       \
  bf16x8 aF[2][4], bF[2][4];                                                   \
  const int nt = (K_) >> 6;                                                    \
  STAGE_A(0, 0, 0); STAGE_A(0, 1, 0); STAGE_B(0, 0, 0); STAGE_B(0, 1, 0);      \
  STAGE_A(1, 0, 64);                                                           \
  asm volatile("s_waitcnt vmcnt(2)" ::: "memory");                             \
  BAR();                                                                       \
  for (int T = 0; T < nt; ++T) {                                               \
    const int c  = T & 1;                                                      \
    const int cn = c ^ 1;                                                      \
    const int k1 = (T + 1) << 6;                                               \
    const int k2 = (T + 2) << 6;                                               \
    const unsigned short* Ac = As + c * 16384;                                 \
    const unsigned short* Bc = Bs + c * 16384;                                 \
    /* P1: read A ib0-1 (8) + B jb0 (4); MFMA ib0-1 x jb0 */                   \
    _Pragma("unroll")                                                          \
    for (int ib = 0; ib < 2; ++ib) {                                           \
      aF[ib][0] = *(const bf16x8*)(Ac + a32 + ib * 2048 + gA0);                \
      aF[ib][1] = *(const bf16x8*)(Ac + a32 + ib * 2048 + gA1);                \
      aF[ib][2] = *(const bf16x8*)(Ac + a32 + ib * 2048 + gA2);                \
      aF[ib][3] = *(const bf16x8*)(Ac + a32 + ib * 2048 + gA3);                \
    }                                                                          \
    bF[0][0] = *(const bf16x8*)(Bc + b32 + gA0);                               \
    bF[0][1] = *(const bf16x8*)(Bc + b32 + gA1);                               \
    bF[0][2] = *(const bf16x8*)(Bc + b32 + gA2);                               \
    bF[0][3] = *(const bf16x8*)(Bc + b32 + gA3);                               \
    if (T + 1 < nt) STAGE_A(cn, 1, k1);                                        \
    BAR();                                                                     \
    __builtin_amdgcn_s_setprio(1);                                             \
    _Pragma("unroll")                                                          \
    for (int s = 0; s < 4; ++s)                                                \
      _Pragma("unroll")                                                        \
      for (int ib = 0; ib < 2; ++ib)                                           \
        acc[ib][0] = MFMA32(aF[ib][s], bF[0][s], acc[ib][0]);                  \
    __builtin_amdgcn_s_setprio(0);                                             \
    BAR();                                                                     \
    /* P2: read B jb1 (4); MFMA ib0-1 x jb1 */                                 \
    bF[1][0] = *(const bf16x8*)(Bc + b32 + 2048 + gA0);                        \
    bF[1][1] = *(const bf16x8*)(Bc + b32 + 2048 + gA1);                        \
    bF[1][2] = *(const bf16x8*)(Bc + b32 + 2048 + gA2);                        \
    bF[1][3] = *(const bf16x8*)(Bc + b32 + 2048 + gA3);                        \
    if (T + 1 < nt) STAGE_B(cn, 0, k1);                                        \
    BAR();                                                                     \
    __builtin_amdgcn_s_setprio(1);                                             \
    _Pragma("unroll")                                                          \
    for (int s = 0; s < 4; ++s)                                                \
      _Pragma("unroll")                                                        \
      for (int ib = 0; ib < 2; ++ib)                                           \
        acc[ib][1] = MFMA32(aF[ib][s], bF[1][s], acc[ib][1]);                  \
    __builtin_amdgcn_s_setprio(0);                                             \
    BAR();                                                                     \
    /* P3: read A ib2-3 (8, overwrite aF); MFMA ib2-3 x jb0 */                 \
    _Pragma("unroll")                                                          \
    for (int ib = 0; ib < 2; ++ib) {                                           \
      aF[ib][0] = *(const bf16x8*)(Ac + a32 + (ib + 2) * 2048 + gA0);          \
      aF[ib][1] = *(const bf16x8*)(Ac + a32 + (ib + 2) * 2048 + gA1);          \
      aF[ib][2] = *(const bf16x8*)(Ac + a32 + (ib + 2) * 2048 + gA2);          \
      aF[ib][3] = *(const bf16x8*)(Ac + a32 + (ib + 2) * 2048 + gA3);          \
    }                                                                          \
    if (T + 1 < nt) STAGE_B(cn, 1, k1);                                        \
    BAR();                                                                     \
    __builtin_amdgcn_s_setprio(1);                                             \
    _Pragma("unroll")                                                          \
    for (int s = 0; s < 4; ++s)                                                \
      _Pragma("unroll")                                                        \
      for (int ib = 0; ib < 2; ++ib)                                           \
        acc[ib + 2][0] = MFMA32(aF[ib][s], bF[0][s], acc[ib + 2][0]);          \
    __builtin_amdgcn_s_setprio(0);                                             \
    BAR();                                                                     \
    /* P4: MFMA ib2-3 x jb1; counted vmcnt */                                  \
    if (T + 2 < nt) STAGE_A(c, 0, k2);                                         \
    __builtin_amdgcn_s_setprio(1);                                             \
    _Pragma("unroll")                                                          \
    for (int s = 0; s < 4; ++s)                                                \
      _Pragma("unroll")                                                        \
      for (int ib = 0; ib < 2; ++ib)                                           \
        acc[ib + 2][1] = MFMA32(aF[ib][s], bF[1][s], acc[ib + 2][1]);          \
    __builtin_amdgcn_s_setprio(0);                                             \
    if (T + 2 < nt) { asm volatile("s_waitcnt vmcnt(2)" ::: "memory"); }       \
    else            { asm volatile("s_waitcnt vmcnt(0)" ::: "memory"); }       \
    BAR();                                                                     \
  }                                                                            \
  const int erow = brow * 256 + wm * 128 + 4 * khalf;                          \
  const int ecol = bcol * 256 + wn * 64 + r31;

// Variant preamble with split A-source: k<1024 from X1 (lda1), k>=1024
// from X2 (lda 1024). Branch in STAGE_A is wave-uniform on k0.
#define GEMM_PREAMBLE_SPLITA(X1_, X2_, lda1_, W_, K_, N_)                      \
  __shared__ unsigned short As[2 * 16384];                                     \
  __shared__ unsigned short Bs[2 * 16384];                                     \
  const int qq  = gridDim.x >> 3;                                              \
  const int swz = (blockIdx.x & 7) * qq + (blockIdx.x >> 3);                   \
  const int tiles_n = (N_) >> 8;                                               \
  const int brow = swz / tiles_n;                                              \
  const int bcol = swz % tiles_n;                                              \
  const int t    = threadIdx.x;                                                \
  const int lane = t & 63;                                                     \
  const int wave = t >> 6;                                                     \
  const int wm   = wave >> 2;                                                  \
  const int wn   = wave & 3;                                                   \
  const int srow = t >> 3;                                                     \
  const int sg   = (t & 7) ^ (srow & 7);                                       \
  const unsigned short* aSrc1 = (X1_) + (size_t)(brow * 256 + srow) * (lda1_) + sg * 8; \
  const unsigned short* aSrc2 = (X2_) + (size_t)(brow * 256 + srow) * 1024 + sg * 8;    \
  const unsigned short* bSrc  = (W_)  + (size_t)(bcol * 256 + srow) * (K_) + sg * 8;    \
  const int wofs = wave * 512;                                                 \
  auto STAGE_A = [&](int buf, int h, int k0) {                                 \
    if (k0 < 1024) {                                                           \
      gload_lds16(aSrc1 + (size_t)(h * 128) * (lda1_) + k0,                    \
                  As + buf * 16384 + (h * 128) * 64 + wofs);                   \
      gload_lds16(aSrc1 + (size_t)(h * 128 + 64) * (lda1_) + k0,               \
                  As + buf * 16384 + (h * 128 + 64) * 64 + wofs);              \
    } else {                                                                   \
      gload_lds16(aSrc2 + (size_t)(h * 128) * 1024 + (k0 - 1024),              \
                  As + buf * 16384 + (h * 128) * 64 + wofs);                   \
      gload_lds16(aSrc2 + (size_t)(h * 128 + 64) * 1024 + (k0 - 1024),         \
                  As + buf * 16384 + (h * 128 + 64) * 64 + wofs);              \
    }                                                                          \
  };                                                                           \
  auto STAGE_B = [&](int buf, int h, int k0) {                                 \
    gload_lds16(bSrc + (size_t)(h * 128) * (K_) + k0,                          \
                Bs + buf * 16384 + (h * 128) * 64 + wofs);                     \
    gload_lds16(bSrc + (size_t)(h * 128 + 64) * (K_) + k0,                     \
                Bs + buf * 16384 + (h * 128 + 64) * 64 + wofs);                \
  };

// ---------- GEMM1: gates. z-blocks -> Zs = sigmoid(z_pre+bz);
//            r-blocks -> Hr = sigmoid(r_pre+br) * h_bf16 (from Xcat) ----------
__global__ __launch_bounds__(512, 2) void gemm_sig(
    const unsigned short* __restrict__ X, const unsigned short* __restrict__ W,
    unsigned short* __restrict__ Zs, unsigned short* __restrict__ Hr,
    int lda, int K, int N,
    const float* __restrict__ bz, const float* __restrict__ br) {
  GEMM_PREAMBLE(X, W, lda, K, N)
  GEMM_KLOOP_BODY(K)
  if (bcol * 256 < 1024) {
#pragma unroll
    for (int ib = 0; ib < 4; ++ib)
#pragma unroll
      for (int jb = 0; jb < 2; ++jb)
#pragma unroll
        for (int g = 0; g < 16; ++g) {
          const int row = erow + ib * 32 + (g & 3) + 8 * (g >> 2);
          const int col = ecol + jb * 32;
          Zs[(size_t)row * 1024 + col] =
              f2bf(sigmoidf_(acc[ib][jb][g] + bz[col]));
        }
  } else {
#pragma unroll
    for (int ib = 0; ib < 4; ++ib)
#pragma unroll
      for (int jb = 0; jb < 2; ++jb)
#pragma unroll
        for (int g = 0; g < 16; ++g) {
          const int row = erow + ib * 32 + (g & 3) + 8 * (g >> 2);
          const int c2 = ecol + jb * 32 - 1024;
          const float hb = bf2f(X[(size_t)row * 2048 + 1024 + c2]);  // bf16 h
          Hr[(size_t)row * 1024 + c2] =
              f2bf(sigmoidf_(acc[ib][jb][g] + br[c2]) * hb);
        }
  }
}

// ---------- GEMM23 merged: acc = [x|Hr] @ [Vh|A]^T (split A-source) --------
// out = h + eps * Zs * tanh(acc + bh)
__global__ __launch_bounds__(512, 2) void gemm_combine2(
    const unsigned short* __restrict__ Xc, const unsigned short* __restrict__ Hr,
    const unsigned short* __restrict__ W, int K, int N,
    const unsigned short* __restrict__ Zs,
    const float* __restrict__ bh, const float* __restrict__ h,
    const float* __restrict__ epsp, float* __restrict__ fout) {
  GEMM_PREAMBLE_SPLITA(Xc, Hr, 2048, W, K, N)
  GEMM_KLOOP_BODY(K)
  const float eps = epsp[0];
#pragma unroll
  for (int ib = 0; ib < 4; ++ib)
#pragma unroll
    for (int jb = 0; jb < 2; ++jb)
#pragma unroll
      for (int g = 0; g < 16; ++g) {
        const int row = erow + ib * 32 + (g & 3) + 8 * (g >> 2);
        const int col = ecol + jb * 32;
        const size_t e = (size_t)row * 1024 + col;
        const float tv = tanhf_(acc[ib][jb][g] + bh[col]);
        fout[e] = h[e] + eps * bf2f(Zs[e]) * tv;
      }
}

// ---------- prep kernels ----------
__global__ void prep_x_kernel(const float* __restrict__ x, const float* __restrict__ h,
                              unsigned short* __restrict__ Xcat) {
  const int total4 = BATCH * 2048 / 4;
  for (int i = blockIdx.x * blockDim.x + threadIdx.x; i < total4; i += gridDim.x * blockDim.x) {
    const int e = i * 4;
    const int m = e >> 11;
    const int c = e & 2047;
    float4 v = (c < 1024) ? *(const float4*)(x + (size_t)m * 1024 + c)
                          : *(const float4*)(h + (size_t)m * 1024 + (c - 1024));
    ushort4 o;
    o.x = f2bf(v.x); o.y = f2bf(v.y); o.z = f2bf(v.z); o.w = f2bf(v.w);
    *(ushort4*)(Xcat + e) = o;
  }
}

__global__ void prep_wcat_kernel(const float* __restrict__ Wz, const float* __restrict__ Uz,
                                 const float* __restrict__ Wr, const float* __restrict__ Ur,
                                 unsigned short* __restrict__ Wcat) {
  const int total4 = 2048 * 2048 / 4;
  for (int i = blockIdx.x * blockDim.x + threadIdx.x; i < total4; i += gridDim.x * blockDim.x) {
    const int e = i * 4;
    const int n = e >> 11;
    const int c = e & 2047;
    const float* src;
    if (n < 1024) src = (c < 1024) ? (Wz + (size_t)n * 1024 + c) : (Uz + (size_t)n * 1024 + c - 1024);
    else          src = (c < 1024) ? (Wr + (size_t)(n - 1024) * 1024 + c) : (Ur + (size_t)(n - 1024) * 1024 + c - 1024);
    float4 v = *(const float4*)src;
    ushort4 o;
    o.x = f2bf(v.x); o.y = f2bf(v.y); o.z = f2bf(v.z); o.w = f2bf(v.w);
    *(ushort4*)(Wcat + e) = o;
  }
}

// Wva[n][0:1024] = bf16(Vh[n]); Wva[n][1024:2048] = bf16(Wh - Wh^T - gamma*I)[n]
__global__ void prep_VA_kernel(const float* __restrict__ Vh, const float* __restrict__ Wh,
                               unsigned short* __restrict__ Wva) {
  const int total4 = 1024 * 2048 / 4;
  for (int i = blockIdx.x * blockDim.x + threadIdx.x; i < total4; i += gridDim.x * blockDim.x) {
    const int e = i * 4;
    const int n = e >> 11;
    const int c = e & 2047;
    ushort4 o;
    if (c < 1024) {
      float4 v = *(const float4*)(Vh + (size_t)n * 1024 + c);
      o.x = f2bf(v.x); o.y = f2bf(v.y); o.z = f2bf(v.z); o.w = f2bf(v.w);
    } else {
      const int cc = c - 1024;
      float4 v = *(const float4*)(Wh + (size_t)n * 1024 + cc);
      float t0 = Wh[(size_t)(cc + 0) * 1024 + n];
      float t1 = Wh[(size_t)(cc + 1) * 1024 + n];
      float t2 = Wh[(size_t)(cc + 2) * 1024 + n];
      float t3 = Wh[(size_t)(cc + 3) * 1024 + n];
      o.x = f2bf(v.x - t0 - ((n == cc + 0) ? GAMMA : 0.0f));
      o.y = f2bf(v.y - t1 - ((n == cc + 1) ? GAMMA : 0.0f));
      o.z = f2bf(v.z - t2 - ((n == cc + 2) ? GAMMA : 0.0f));
      o.w = f2bf(v.w - t3 - ((n == cc + 3) ? GAMMA : 0.0f));
    }
    *(ushort4*)(Wva + e) = o;
  }
}

// ---------- launch ----------
extern "C" void kernel_launch(void* const* d_in, const int* in_sizes, int n_in,
                              void* d_out, int out_size, void* d_ws, size_t ws_size,
                              hipStream_t stream) {
  const float* x   = (const float*)d_in[0];
  const float* h   = (const float*)d_in[1];
  const float* Wz  = (const float*)d_in[2];
  const float* bz  = (const float*)d_in[3];
  const float* Uz  = (const float*)d_in[4];
  const float* Wr  = (const float*)d_in[5];
  const float* br  = (const float*)d_in[6];
  const float* Ur  = (const float*)d_in[7];
  const float* Vh  = (const float*)d_in[8];
  const float* bh  = (const float*)d_in[9];
  const float* Wh  = (const float*)d_in[10];
  const float* eps = (const float*)d_in[11];
  float* out = (float*)d_out;

  char* ws = (char*)d_ws;
  size_t off = 0;
  unsigned short* Xcat = (unsigned short*)(ws + off); off += (size_t)BATCH * 2048 * 2;
  unsigned short* Wcat = (unsigned short*)(ws + off); off += (size_t)2048 * 2048 * 2;
  unsigned short* Wva  = (unsigned short*)(ws + off); off += (size_t)1024 * 2048 * 2;
  unsigned short* Zs   = (unsigned short*)(ws + off); off += (size_t)BATCH * 1024 * 2;
  unsigned short* Hr   = (unsigned short*)(ws + off); off += (size_t)BATCH * 1024 * 2;

  dim3 blk(256);
  prep_x_kernel<<<2048, blk, 0, stream>>>(x, h, Xcat);
  prep_wcat_kernel<<<1024, blk, 0, stream>>>(Wz, Uz, Wr, Ur, Wcat);
  prep_VA_kernel<<<512, blk, 0, stream>>>(Vh, Wh, Wva);

  dim3 gblk(512);
  // GEMM1: z-blocks -> Zs, r-blocks -> Hr (fused sigmoid/mul epilogues)
  gemm_sig<<<(BATCH / 256) * (2048 / 256), gblk, 0, stream>>>(
      Xcat, Wcat, Zs, Hr, 2048, 2048, 2048, bz, br);
  // GEMM23: out = h + eps*Zs*tanh([x|Hr] @ [Vh|A]^T + bh)
  gemm_combine2<<<(BATCH / 256) * (1024 / 256), gblk, 0, stream>>>(
      Xcat, Hr, Wva, 2048, 1024, Zs, bh, h, eps, out);
}

// Round 12
// 271.644 us; speedup vs baseline: 1.1054x; 1.1054x over previous
//
#include <hip/hip_runtime.h>
#include <hip/hip_bf16.h>
#include <stdint.h>

#define BATCH  16384
#define GAMMA  0.01f

using f32x4  = __attribute__((ext_vector_type(4))) float;
using bf16x8 = __attribute__((ext_vector_type(8))) __bf16;

#define MFMA16(a, b, c) __builtin_amdgcn_mfma_f32_16x16x32_bf16((a), (b), (c), 0, 0, 0)
#define BAR() asm volatile("s_barrier" ::: "memory")

// ---------- helpers ----------
__device__ __forceinline__ unsigned short f2bf(float f) {
  unsigned int u = __float_as_uint(f);
  unsigned int r = (u + 0x7fffu + ((u >> 16) & 1u)) >> 16;  // RNE
  return (unsigned short)r;
}
__device__ __forceinline__ float bf2f(unsigned short u) {
  return __uint_as_float(((unsigned int)u) << 16);
}
__device__ __forceinline__ float sigmoidf_(float x) {
  return 1.0f / (1.0f + __expf(-x));
}
__device__ __forceinline__ float tanhf_(float x) {
  float e = __expf(2.0f * x);
  return (e - 1.0f) / (e + 1.0f);
}
__device__ __forceinline__ void gload_lds16(const void* gsrc, void* ldst) {
  __builtin_amdgcn_global_load_lds(
      (const __attribute__((address_space(1))) void*)gsrc,
      (__attribute__((address_space(3))) void*)ldst, 16, 0, 0);
}

// =====================================================================
// R5/R9-verified K-loop, 16x16x32 MFMA. DO NOT MODIFY.
// Schedule: P1: STAGE_A(cn,1,k1) P2: STAGE_B(cn,0,k1) P3: STAGE_B(cn,1,k1)
//           P4: STAGE_A(c,0,k2) + counted vmcnt(2); 2 barriers/phase.
// Deviations measured worse: R3=565, R6=942, R7=838, R8=715 TF.
// MFMA shape: 16x16 read pattern = 0 bank conflicts (R5-R9);
//             32x32 pattern = 1.26e7 conflicts, net LOSS (R11). Keep 16x16.
// =====================================================================
#define GEMM_KLOOP_BODY(K_)                                                    \
  f32x4 acc[8][4] = {};                                                        \
  bf16x8 aR[4][2], bR[4][2];                                                   \
  const int lr   = lane & 15;                                                  \
  const int kq8  = (lane >> 4) * 8;                                            \
  const int sx   = (lr & 7) << 3;                                              \
  const int koff0 = kq8 ^ sx;                                                  \
  const int koff1 = (32 + kq8) ^ sx;                                           \
  const int aBase = (wm * 128 + lr) * 64;                                      \
  const int bBase = (wn * 64 + lr) * 64;                                       \
  const int nt = (K_) >> 6;                                                    \
  STAGE_A(0, 0, 0); STAGE_A(0, 1, 0); STAGE_B(0, 0, 0); STAGE_B(0, 1, 0);      \
  STAGE_A(1, 0, 64);                                                           \
  asm volatile("s_waitcnt vmcnt(2)" ::: "memory");                             \
  BAR();                                                                       \
  for (int T = 0; T < nt; ++T) {                                               \
    const int c  = T & 1;                                                      \
    const int cn = c ^ 1;                                                      \
    const int k1 = (T + 1) << 6;                                               \
    const int k2 = (T + 2) << 6;                                               \
    const unsigned short* Ac = As + c * 16384;                                 \
    const unsigned short* Bc = Bs + c * 16384;                                 \
    /* P1 */                                                                   \
    _Pragma("unroll")                                                          \
    for (int i = 0; i < 4; ++i) {                                              \
      aR[i][0] = *(const bf16x8*)(Ac + aBase + i * 1024 + koff0);              \
      aR[i][1] = *(const bf16x8*)(Ac + aBase + i * 1024 + koff1);              \
    }                                                                          \
    _Pragma("unroll")                                                          \
    for (int j = 0; j < 2; ++j) {                                              \
      bR[j][0] = *(const bf16x8*)(Bc + bBase + j * 1024 + koff0);              \
      bR[j][1] = *(const bf16x8*)(Bc + bBase + j * 1024 + koff1);              \
    }                                                                          \
    if (T + 1 < nt) STAGE_A(cn, 1, k1);                                        \
    BAR();                                                                     \
    __builtin_amdgcn_s_setprio(1);                                             \
    _Pragma("unroll")                                                          \
    for (int i = 0; i < 4; ++i)                                                \
      _Pragma("unroll")                                                        \
      for (int j = 0; j < 2; ++j) {                                            \
        acc[i][j] = MFMA16(aR[i][0], bR[j][0], acc[i][j]);                     \
        acc[i][j] = MFMA16(aR[i][1], bR[j][1], acc[i][j]);                     \
      }                                                                        \
    __builtin_amdgcn_s_setprio(0);                                             \
    BAR();                                                                     \
    /* P2 */                                                                   \
    _Pragma("unroll")                                                          \
    for (int j = 2; j < 4; ++j) {                                              \
      bR[j][0] = *(const bf16x8*)(Bc + bBase + j * 1024 + koff0);              \
      bR[j][1] = *(const bf16x8*)(Bc + bBase + j * 1024 + koff1);              \
    }                                                                          \
    if (T + 1 < nt) STAGE_B(cn, 0, k1);                                        \
    BAR();                                                                     \
    __builtin_amdgcn_s_setprio(1);                                             \
    _Pragma("unroll")                                                          \
    for (int i = 0; i < 4; ++i)                                                \
      _Pragma("unroll")                                                        \
      for (int j = 2; j < 4; ++j) {                                            \
        acc[i][j] = MFMA16(aR[i][0], bR[j][0], acc[i][j]);                     \
        acc[i][j] = MFMA16(aR[i][1], bR[j][1], acc[i][j]);                     \
      }                                                                        \
    __builtin_amdgcn_s_setprio(0);                                             \
    BAR();                                                                     \
    /* P3 */                                                                   \
    _Pragma("unroll")                                                          \
    for (int i = 0; i < 4; ++i) {                                              \
      aR[i][0] = *(const bf16x8*)(Ac + aBase + (i + 4) * 1024 + koff0);        \
      aR[i][1] = *(const bf16x8*)(Ac + aBase + (i + 4) * 1024 + koff1);        \
    }                                                                          \
    if (T + 1 < nt) STAGE_B(cn, 1, k1);                                        \
    BAR();                                                                     \
    __builtin_amdgcn_s_setprio(1);                                             \
    _Pragma("unroll")                                                          \
    for (int i = 0; i < 4; ++i)                                                \
      _Pragma("unroll")                                                        \
      for (int j = 0; j < 2; ++j) {                                            \
        acc[i + 4][j] = MFMA16(aR[i][0], bR[j][0], acc[i + 4][j]);             \
        acc[i + 4][j] = MFMA16(aR[i][1], bR[j][1], acc[i + 4][j]);             \
      }                                                                        \
    __builtin_amdgcn_s_setprio(0);                                             \
    BAR();                                                                     \
    /* P4 */                                                                   \
    if (T + 2 < nt) STAGE_A(c, 0, k2);                                         \
    __builtin_amdgcn_s_setprio(1);                                             \
    _Pragma("unroll")                                                          \
    for (int i = 0; i < 4; ++i)                                                \
      _Pragma("unroll")                                                        \
      for (int j = 2; j < 4; ++j) {                                            \
        acc[i + 4][j] = MFMA16(aR[i][0], bR[j][0], acc[i + 4][j]);             \
        acc[i + 4][j] = MFMA16(aR[i][1], bR[j][1], acc[i + 4][j]);             \
      }                                                                        \
    __builtin_amdgcn_s_setprio(0);                                             \
    if (T + 2 < nt) { asm volatile("s_waitcnt vmcnt(2)" ::: "memory"); }       \
    else            { asm volatile("s_waitcnt vmcnt(0)" ::: "memory"); }       \
    BAR();                                                                     \
  }                                                                            \
  const int rbase = brow * 256 + wm * 128 + (lane >> 4) * 4;                   \
  const int cbase = bcol * 256 + wn * 64 + lr;

#define GEMM_PREAMBLE(X_, W_, lda_, K_, N_)                                    \
  __shared__ unsigned short As[2 * 16384];                                     \
  __shared__ unsigned short Bs[2 * 16384];                                     \
  const int qq  = gridDim.x >> 3;                                              \
  const int swz = (blockIdx.x & 7) * qq + (blockIdx.x >> 3);                   \
  const int tiles_n = (N_) >> 8;                                               \
  const int brow = swz / tiles_n;                                              \
  const int bcol = swz % tiles_n;                                              \
  const int t    = threadIdx.x;                                                \
  const int lane = t & 63;                                                     \
  const int wave = t >> 6;                                                     \
  const int wm   = wave >> 2;                                                  \
  const int wn   = wave & 3;                                                   \
  const int srow = t >> 3;                                                     \
  const int sg   = (t & 7) ^ (srow & 7);                                       \
  const unsigned short* aSrc = (X_) + (size_t)(brow * 256 + srow) * (lda_) + sg * 8; \
  const unsigned short* bSrc = (W_) + (size_t)(bcol * 256 + srow) * (K_) + sg * 8;   \
  const int wofs = wave * 512;                                                 \
  auto STAGE_A = [&](int buf, int h, int k0) {                                 \
    gload_lds16(aSrc + (size_t)(h * 128) * (lda_) + k0,                        \
                As + buf * 16384 + (h * 128) * 64 + wofs);                     \
    gload_lds16(aSrc + (size_t)(h * 128 + 64) * (lda_) + k0,                   \
                As + buf * 16384 + (h * 128 + 64) * 64 + wofs);                \
  };                                                                           \
  auto STAGE_B = [&](int buf, int h, int k0) {                                 \
    gload_lds16(bSrc + (size_t)(h * 128) * (K_) + k0,                          \
                Bs + buf * 16384 + (h * 128) * 64 + wofs);                     \
    gload_lds16(bSrc + (size_t)(h * 128 + 64) * (K_) + k0,                     \
                Bs + buf * 16384 + (h * 128 + 64) * 64 + wofs);                \
  };

// Split A-source: k<1024 from X1 (lda1), k>=1024 from X2 (lda 1024).
#define GEMM_PREAMBLE_SPLITA(X1_, X2_, lda1_, W_, K_, N_)                      \
  __shared__ unsigned short As[2 * 16384];                                     \
  __shared__ unsigned short Bs[2 * 16384];                                     \
  const int qq  = gridDim.x >> 3;                                              \
  const int swz = (blockIdx.x & 7) * qq + (blockIdx.x >> 3);                   \
  const int tiles_n = (N_) >> 8;                                               \
  const int brow = swz / tiles_n;                                              \
  const int bcol = swz % tiles_n;                                              \
  const int t    = threadIdx.x;                                                \
  const int lane = t & 63;                                                     \
  const int wave = t >> 6;                                                     \
  const int wm   = wave >> 2;                                                  \
  const int wn   = wave & 3;                                                   \
  const int srow = t >> 3;                                                     \
  const int sg   = (t & 7) ^ (srow & 7);                                       \
  const unsigned short* aSrc1 = (X1_) + (size_t)(brow * 256 + srow) * (lda1_) + sg * 8; \
  const unsigned short* aSrc2 = (X2_) + (size_t)(brow * 256 + srow) * 1024 + sg * 8;    \
  const unsigned short* bSrc  = (W_)  + (size_t)(bcol * 256 + srow) * (K_) + sg * 8;    \
  const int wofs = wave * 512;                                                 \
  auto STAGE_A = [&](int buf, int h, int k0) {                                 \
    if (k0 < 1024) {                                                           \
      gload_lds16(aSrc1 + (size_t)(h * 128) * (lda1_) + k0,                    \
                  As + buf * 16384 + (h * 128) * 64 + wofs);                   \
      gload_lds16(aSrc1 + (size_t)(h * 128 + 64) * (lda1_) + k0,               \
                  As + buf * 16384 + (h * 128 + 64) * 64 + wofs);              \
    } else {                                                                   \
      gload_lds16(aSrc2 + (size_t)(h * 128) * 1024 + (k0 - 1024),              \
                  As + buf * 16384 + (h * 128) * 64 + wofs);                   \
      gload_lds16(aSrc2 + (size_t)(h * 128 + 64) * 1024 + (k0 - 1024),         \
                  As + buf * 16384 + (h * 128 + 64) * 64 + wofs);              \
    }                                                                          \
  };                                                                           \
  auto STAGE_B = [&](int buf, int h, int k0) {                                 \
    gload_lds16(bSrc + (size_t)(h * 128) * (K_) + k0,                          \
                Bs + buf * 16384 + (h * 128) * 64 + wofs);                     \
    gload_lds16(bSrc + (size_t)(h * 128 + 64) * (K_) + k0,                     \
                Bs + buf * 16384 + (h * 128 + 64) * 64 + wofs);                \
  };

// ---------- GEMM1: gates. z-blocks -> Zs = sigmoid(z_pre+bz);
//            r-blocks -> Hr = sigmoid(r_pre+br) * h_bf16 (from Xcat) --------
__global__ __launch_bounds__(512, 2) void gemm_sig(
    const unsigned short* __restrict__ X, const unsigned short* __restrict__ W,
    unsigned short* __restrict__ Zs, unsigned short* __restrict__ Hr,
    int lda, int K, int N,
    const float* __restrict__ bz, const float* __restrict__ br) {
  GEMM_PREAMBLE(X, W, lda, K, N)
  GEMM_KLOOP_BODY(K)
  if (bcol * 256 < 1024) {
#pragma unroll
    for (int i = 0; i < 8; ++i)
#pragma unroll
      for (int j = 0; j < 4; ++j)
#pragma unroll
        for (int q = 0; q < 4; ++q) {
          const int col = cbase + j * 16;
          Zs[(size_t)(rbase + i * 16 + q) * 1024 + col] =
              f2bf(sigmoidf_(acc[i][j][q] + bz[col]));
        }
  } else {
#pragma unroll
    for (int i = 0; i < 8; ++i)
#pragma unroll
      for (int j = 0; j < 4; ++j)
#pragma unroll
        for (int q = 0; q < 4; ++q) {
          const int row = rbase + i * 16 + q;
          const int c2 = cbase + j * 16 - 1024;
          const float hb = bf2f(X[(size_t)row * 2048 + 1024 + c2]);  // bf16 h
          Hr[(size_t)row * 1024 + c2] =
              f2bf(sigmoidf_(acc[i][j][q] + br[c2]) * hb);
        }
  }
}

// ---------- GEMM23 merged: acc = [x|Hr] @ [Vh|A]^T (split A-source) --------
// out = h_bf16 + eps * Zs * tanh(acc + bh)   (h from Xcat's h-half)
__global__ __launch_bounds__(512, 2) void gemm_combine2(
    const unsigned short* __restrict__ Xc, const unsigned short* __restrict__ Hr,
    const unsigned short* __restrict__ W, int K, int N,
    const unsigned short* __restrict__ Zs,
    const float* __restrict__ bh,
    const float* __restrict__ epsp, float* __restrict__ fout) {
  GEMM_PREAMBLE_SPLITA(Xc, Hr, 2048, W, K, N)
  GEMM_KLOOP_BODY(K)
  const float eps = epsp[0];
#pragma unroll
  for (int i = 0; i < 8; ++i)
#pragma unroll
    for (int j = 0; j < 4; ++j)
#pragma unroll
      for (int q = 0; q < 4; ++q) {
        const int row = rbase + i * 16 + q;
        const int col = cbase + j * 16;
        const size_t e = (size_t)row * 1024 + col;
        const float hb = bf2f(Xc[(size_t)row * 2048 + 1024 + col]);  // bf16 h
        const float tv = tanhf_(acc[i][j][q] + bh[col]);
        fout[e] = hb + eps * bf2f(Zs[e]) * tv;
      }
}

// ---------- prep kernels ----------
__global__ void prep_x_kernel(const float* __restrict__ x, const float* __restrict__ h,
                              unsigned short* __restrict__ Xcat) {
  const int total4 = BATCH * 2048 / 4;
  for (int i = blockIdx.x * blockDim.x + threadIdx.x; i < total4; i += gridDim.x * blockDim.x) {
    const int e = i * 4;
    const int m = e >> 11;
    const int c = e & 2047;
    float4 v = (c < 1024) ? *(const float4*)(x + (size_t)m * 1024 + c)
                          : *(const float4*)(h + (size_t)m * 1024 + (c - 1024));
    ushort4 o;
    o.x = f2bf(v.x); o.y = f2bf(v.y); o.z = f2bf(v.z); o.w = f2bf(v.w);
    *(ushort4*)(Xcat + e) = o;
  }
}

__global__ void prep_wcat_kernel(const float* __restrict__ Wz, const float* __restrict__ Uz,
                                 const float* __restrict__ Wr, const float* __restrict__ Ur,
                                 unsigned short* __restrict__ Wcat) {
  const int total4 = 2048 * 2048 / 4;
  for (int i = blockIdx.x * blockDim.x + threadIdx.x; i < total4; i += gridDim.x * blockDim.x) {
    const int e = i * 4;
    const int n = e >> 11;
    const int c = e & 2047;
    const float* src;
    if (n < 1024) src = (c < 1024) ? (Wz + (size_t)n * 1024 + c) : (Uz + (size_t)n * 1024 + c - 1024);
    else          src = (c < 1024) ? (Wr + (size_t)(n - 1024) * 1024 + c) : (Ur + (size_t)(n - 1024) * 1024 + c - 1024);
    float4 v = *(const float4*)src;
    ushort4 o;
    o.x = f2bf(v.x); o.y = f2bf(v.y); o.z = f2bf(v.z); o.w = f2bf(v.w);
    *(ushort4*)(Wcat + e) = o;
  }
}

// Wva[n][0:1024] = bf16(Vh[n]); Wva[n][1024:2048] = bf16(Wh - Wh^T - gamma*I)[n]
__global__ void prep_VA_kernel(const float* __restrict__ Vh, const float* __restrict__ Wh,
                               unsigned short* __restrict__ Wva) {
  const int total4 = 1024 * 2048 / 4;
  for (int i = blockIdx.x * blockDim.x + threadIdx.x; i < total4; i += gridDim.x * blockDim.x) {
    const int e = i * 4;
    const int n = e >> 11;
    const int c = e & 2047;
    ushort4 o;
    if (c < 1024) {
      float4 v = *(const float4*)(Vh + (size_t)n * 1024 + c);
      o.x = f2bf(v.x); o.y = f2bf(v.y); o.z = f2bf(v.z); o.w = f2bf(v.w);
    } else {
      const int cc = c - 1024;
      float4 v = *(const float4*)(Wh + (size_t)n * 1024 + cc);
      float t0 = Wh[(size_t)(cc + 0) * 1024 + n];
      float t1 = Wh[(size_t)(cc + 1) * 1024 + n];
      float t2 = Wh[(size_t)(cc + 2) * 1024 + n];
      float t3 = Wh[(size_t)(cc + 3) * 1024 + n];
      o.x = f2bf(v.x - t0 - ((n == cc + 0) ? GAMMA : 0.0f));
      o.y = f2bf(v.y - t1 - ((n == cc + 1) ? GAMMA : 0.0f));
      o.z = f2bf(v.z - t2 - ((n == cc + 2) ? GAMMA : 0.0f));
      o.w = f2bf(v.w - t3 - ((n == cc + 3) ? GAMMA : 0.0f));
    }
    *(ushort4*)(Wva + e) = o;
  }
}

// ---------- launch ----------
extern "C" void kernel_launch(void* const* d_in, const int* in_sizes, int n_in,
                              void* d_out, int out_size, void* d_ws, size_t ws_size,
                              hipStream_t stream) {
  const float* x   = (const float*)d_in[0];
  const float* h   = (const float*)d_in[1];
  const float* Wz  = (const float*)d_in[2];
  const float* bz  = (const float*)d_in[3];
  const float* Uz  = (const float*)d_in[4];
  const float* Wr  = (const float*)d_in[5];
  const float* br  = (const float*)d_in[6];
  const float* Ur  = (const float*)d_in[7];
  const float* Vh  = (const float*)d_in[8];
  const float* bh  = (const float*)d_in[9];
  const float* Wh  = (const float*)d_in[10];
  const float* eps = (const float*)d_in[11];
  float* out = (float*)d_out;

  char* ws = (char*)d_ws;
  size_t off = 0;
  unsigned short* Xcat = (unsigned short*)(ws + off); off += (size_t)BATCH * 2048 * 2;
  unsigned short* Wcat = (unsigned short*)(ws + off); off += (size_t)2048 * 2048 * 2;
  unsigned short* Wva  = (unsigned short*)(ws + off); off += (size_t)1024 * 2048 * 2;
  unsigned short* Zs   = (unsigned short*)(ws + off); off += (size_t)BATCH * 1024 * 2;
  unsigned short* Hr   = (unsigned short*)(ws + off); off += (size_t)BATCH * 1024 * 2;

  dim3 blk(256);
  prep_x_kernel<<<2048, blk, 0, stream>>>(x, h, Xcat);
  prep_wcat_kernel<<<1024, blk, 0, stream>>>(Wz, Uz, Wr, Ur, Wcat);
  prep_VA_kernel<<<512, blk, 0, stream>>>(Vh, Wh, Wva);

  dim3 gblk(512);
  // GEMM1: z-blocks -> Zs, r-blocks -> Hr (fused sigmoid/mul epilogues)
  gemm_sig<<<(BATCH / 256) * (2048 / 256), gblk, 0, stream>>>(
      Xcat, Wcat, Zs, Hr, 2048, 2048, 2048, bz, br);
  // GEMM23: out = h + eps*Zs*tanh([x|Hr] @ [Vh|A]^T + bh)
  gemm_combine2<<<(BATCH / 256) * (1024 / 256), gblk, 0, stream>>>(
      Xcat, Hr, Wva, 2048, 1024, Zs, bh, eps, out);
}